// Round 1
// baseline (1938.506 us; speedup 1.0000x reference)
//
#include <hip/hip_runtime.h>
#include <cstdint>

#define N_NODES 50000
#define N_EDGES 800000
#define EP (N_EDGES + N_NODES)   // edges + self-loops
#define IN_DIM 32
#define HID 64
#define HEADS 4
#define HC 256                   // HID*HEADS
#define OUT_DIM 128
#define NEG_SLOPE 0.2f
#define LN_EPS 1e-5f

// ---------------- input projection + ELU: h = elu(x @ W_in + b_in) ----------
__global__ void k_in_proj(const float* __restrict__ x, const float* __restrict__ W,
                          const float* __restrict__ b, float* __restrict__ out) {
    int g = blockIdx.x * blockDim.x + threadIdx.x;   // N*HID threads, exact
    int n = g >> 6, j = g & 63;
    const float* xr = x + n * IN_DIM;
    float acc = b[j];
#pragma unroll
    for (int k = 0; k < IN_DIM; ++k) acc += xr[k] * W[k * HID + j];
    out[g] = acc > 0.f ? acc : (expf(acc) - 1.f);
}

// ---- lin + attention dots: hh = x @ W; a_src[n,h] = <hh[n,h,:], att_s[h,:]> ----
// NPB nodes per 256-thread block; thread j owns output column j (j = h*64+c).
template <int K, int NPB>
__global__ void k_lin_att(const float* __restrict__ x, const float* __restrict__ W,
                          const float* __restrict__ att_s, const float* __restrict__ att_d,
                          float* __restrict__ hh, float* __restrict__ a_src,
                          float* __restrict__ a_dst) {
    __shared__ float xs[NPB][K];
    const int n0 = blockIdx.x * NPB;
    const int j = threadIdx.x;                  // 0..255
    for (int t = threadIdx.x; t < NPB * K; t += 256) {
        int i = t / K, k = t - i * K;
        xs[i][k] = x[(n0 + i) * K + k];         // N divisible by NPB: no tail
    }
    __syncthreads();
    float acc[NPB];
#pragma unroll
    for (int i = 0; i < NPB; ++i) acc[i] = 0.f;
    for (int k = 0; k < K; ++k) {
        float wk = W[k * HC + j];
#pragma unroll
        for (int i = 0; i < NPB; ++i) acc[i] += xs[i][k] * wk;
    }
    const int h = j >> 6, c = j & 63;
    const float ws = att_s[h * HID + c];
    const float wd = att_d[h * HID + c];
#pragma unroll
    for (int i = 0; i < NPB; ++i) {
        int n = n0 + i;
        float v = acc[i];
        hh[n * HC + j] = v;
        float rs = v * ws, rd = v * wd;
#pragma unroll
        for (int off = 32; off > 0; off >>= 1) {
            rs += __shfl_down(rs, off, 64);
            rd += __shfl_down(rd, off, 64);
        }
        if (c == 0) { a_src[n * HEADS + h] = rs; a_dst[n * HEADS + h] = rd; }
    }
}

// ---- edge pass 1: p = exp(leaky_relu(a_src[s]+a_dst[d])); denom[d] += p ----
// (segment-max subtraction omitted: softmax is shift-invariant and |e| is O(1))
__global__ void k_edge_p(const int* __restrict__ ei, const float* __restrict__ a_src,
                         const float* __restrict__ a_dst, float* __restrict__ p_buf,
                         float* __restrict__ denom) {
    int g = blockIdx.x * blockDim.x + threadIdx.x;
    if (g >= EP * HEADS) return;
    int e = g >> 2, h = g & 3;
    int s, d;
    if (e < N_EDGES) { s = ei[e]; d = ei[N_EDGES + e]; } else { s = d = e - N_EDGES; }
    float ev = a_src[s * HEADS + h] + a_dst[d * HEADS + h];
    ev = ev > 0.f ? ev : NEG_SLOPE * ev;
    float p = __expf(ev);
    p_buf[g] = p;
    atomicAdd(&denom[d * HEADS + h], p);
}

// ---- edge pass 2: num[d, j] += p[e, j/64] * hh[s, j]  (one block per edge) ----
__global__ void k_edge_msg(const int* __restrict__ ei, const float* __restrict__ p_buf,
                           const float* __restrict__ hh, float* __restrict__ num) {
    int e = blockIdx.x;
    int j = threadIdx.x;
    int s, d;
    if (e < N_EDGES) { s = ei[e]; d = ei[N_EDGES + e]; } else { s = d = e - N_EDGES; }
    float p = p_buf[e * HEADS + (j >> 6)];
    atomicAdd(&num[d * HC + j], p * hh[s * HC + j]);
}

// ---- finalize: out = elu(num/(denom+1e-16) + bias) ----
__global__ void k_node_fin(const float* __restrict__ num, const float* __restrict__ denom,
                           const float* __restrict__ bias, float* __restrict__ out) {
    int g = blockIdx.x * blockDim.x + threadIdx.x;    // N*HC threads, exact
    int n = g >> 8;
    int h = (g >> 6) & 3;
    float v = num[g] / (denom[n * HEADS + h] + 1e-16f) + bias[g & 255];
    out[g] = v > 0.f ? v : (expf(v) - 1.f);
}

// ---- out proj + LayerNorm: block of 128 threads handles NPB nodes ----
template <int NPB>
__global__ void k_out_ln(const float* __restrict__ x, const float* __restrict__ W,
                         const float* __restrict__ b, const float* __restrict__ gamma,
                         const float* __restrict__ beta, float* __restrict__ out) {
    __shared__ float xs[NPB][HC];
    __shared__ float red[2][NPB][2];
    const int n0 = blockIdx.x * NPB;
    const int j = threadIdx.x;                 // 0..127
    for (int t = threadIdx.x; t < NPB * HC; t += 128) {
        int i = t >> 8, k = t & 255;
        xs[i][k] = x[(n0 + i) * HC + k];
    }
    __syncthreads();
    float acc[NPB];
#pragma unroll
    for (int i = 0; i < NPB; ++i) acc[i] = b[j];
    for (int k = 0; k < HC; ++k) {
        float wk = W[k * OUT_DIM + j];
#pragma unroll
        for (int i = 0; i < NPB; ++i) acc[i] += xs[i][k] * wk;
    }
    const int wave = j >> 6, lane = j & 63;
#pragma unroll
    for (int i = 0; i < NPB; ++i) {
        float s = acc[i], s2 = acc[i] * acc[i];
#pragma unroll
        for (int off = 32; off > 0; off >>= 1) {
            s += __shfl_down(s, off, 64);
            s2 += __shfl_down(s2, off, 64);
        }
        if (lane == 0) { red[wave][i][0] = s; red[wave][i][1] = s2; }
    }
    __syncthreads();
#pragma unroll
    for (int i = 0; i < NPB; ++i) {
        int n = n0 + i;
        float s = red[0][i][0] + red[1][i][0];
        float s2 = red[0][i][1] + red[1][i][1];
        float mu = s * (1.f / OUT_DIM);
        float var = s2 * (1.f / OUT_DIM) - mu * mu;
        float inv = rsqrtf(var + LN_EPS);
        out[n * OUT_DIM + j] = (acc[i] - mu) * inv * gamma[j] + beta[j];
    }
}

extern "C" void kernel_launch(void* const* d_in, const int* in_sizes, int n_in,
                              void* d_out, int out_size, void* d_ws, size_t ws_size,
                              hipStream_t stream) {
    const float* x        = (const float*)d_in[0];
    const int*   ei       = (const int*)  d_in[1];
    const float* W_in     = (const float*)d_in[2];
    const float* b_in     = (const float*)d_in[3];
    const float* lin0_w   = (const float*)d_in[4];
    const float* att0_src = (const float*)d_in[5];
    const float* att0_dst = (const float*)d_in[6];
    const float* bias0    = (const float*)d_in[7];
    const float* lin1_w   = (const float*)d_in[8];
    const float* att1_src = (const float*)d_in[9];
    const float* att1_dst = (const float*)d_in[10];
    const float* bias1    = (const float*)d_in[11];
    const float* W_out    = (const float*)d_in[12];
    const float* b_out    = (const float*)d_in[13];
    const float* ln_gamma = (const float*)d_in[14];
    const float* ln_beta  = (const float*)d_in[15];
    float* out = (float*)d_out;

    float* ws    = (float*)d_ws;
    float* h_in  = ws;                            // N*HID
    float* A     = h_in + (size_t)N_NODES * HID;  // N*HC
    float* B     = A + (size_t)N_NODES * HC;      // N*HC
    float* a_src = B + (size_t)N_NODES * HC;      // N*HEADS
    float* a_dst = a_src + (size_t)N_NODES * HEADS;
    float* denom = a_dst + (size_t)N_NODES * HEADS;
    float* p_buf = denom + (size_t)N_NODES * HEADS;  // EP*HEADS

    const size_t nhc_bytes = (size_t)N_NODES * HC * sizeof(float);
    const size_t den_bytes = (size_t)N_NODES * HEADS * sizeof(float);

    // 1. input projection
    k_in_proj<<<(N_NODES * HID) / 256, 256, 0, stream>>>(x, W_in, b_in, h_in);

    // ---- GAT layer 0 ----
    k_lin_att<HID, 8><<<N_NODES / 8, 256, 0, stream>>>(h_in, lin0_w, att0_src, att0_dst,
                                                       A, a_src, a_dst);
    hipMemsetAsync(B, 0, nhc_bytes, stream);
    hipMemsetAsync(denom, 0, den_bytes, stream);
    k_edge_p<<<(EP * HEADS + 255) / 256, 256, 0, stream>>>(ei, a_src, a_dst, p_buf, denom);
    k_edge_msg<<<EP, 256, 0, stream>>>(ei, p_buf, A, B);
    k_node_fin<<<(N_NODES * HC) / 256, 256, 0, stream>>>(B, denom, bias0, A);  // x1 -> A

    // ---- GAT layer 1 ----
    k_lin_att<HC, 8><<<N_NODES / 8, 256, 0, stream>>>(A, lin1_w, att1_src, att1_dst,
                                                      B, a_src, a_dst);       // hh1 -> B
    hipMemsetAsync(A, 0, nhc_bytes, stream);
    hipMemsetAsync(denom, 0, den_bytes, stream);
    k_edge_p<<<(EP * HEADS + 255) / 256, 256, 0, stream>>>(ei, a_src, a_dst, p_buf, denom);
    k_edge_msg<<<EP, 256, 0, stream>>>(ei, p_buf, B, A);
    k_node_fin<<<(N_NODES * HC) / 256, 256, 0, stream>>>(A, denom, bias1, B);  // x2 -> B

    // ---- output projection + LayerNorm ----
    k_out_ln<4><<<N_NODES / 4, 128, 0, stream>>>(B, W_out, b_out, ln_gamma, ln_beta, out);
}

// Round 2
// 977.954 us; speedup vs baseline: 1.9822x; 1.9822x over previous
//
#include <hip/hip_runtime.h>
#include <cstdint>

#define N_NODES 50000
#define N_EDGES 800000
#define EP (N_EDGES + N_NODES)   // edges + self-loops
#define IN_DIM 32
#define HID 64
#define HEADS 4
#define HC 256                   // HID*HEADS
#define OUT_DIM 128
#define NEG_SLOPE 0.2f
#define LN_EPS 1e-5f

// ---------------- input projection + ELU: h = elu(x @ W_in + b_in) ----------
__global__ void k_in_proj(const float* __restrict__ x, const float* __restrict__ W,
                          const float* __restrict__ b, float* __restrict__ out) {
    int g = blockIdx.x * blockDim.x + threadIdx.x;   // N*HID threads, exact
    int n = g >> 6, j = g & 63;
    const float* xr = x + n * IN_DIM;
    float acc = b[j];
#pragma unroll
    for (int k = 0; k < IN_DIM; ++k) acc += xr[k] * W[k * HID + j];
    out[g] = acc > 0.f ? acc : (expf(acc) - 1.f);
}

// ---- lin + attention dots: hh = x @ W; a_src[n,h] = <hh[n,h,:], att_s[h,:]> ----
template <int K, int NPB>
__global__ void k_lin_att(const float* __restrict__ x, const float* __restrict__ W,
                          const float* __restrict__ att_s, const float* __restrict__ att_d,
                          float* __restrict__ hh, float* __restrict__ a_src,
                          float* __restrict__ a_dst) {
    __shared__ float xs[NPB][K];
    const int n0 = blockIdx.x * NPB;
    const int j = threadIdx.x;                  // 0..255
    for (int t = threadIdx.x; t < NPB * K; t += 256) {
        int i = t / K, k = t - i * K;
        xs[i][k] = x[(n0 + i) * K + k];
    }
    __syncthreads();
    float acc[NPB];
#pragma unroll
    for (int i = 0; i < NPB; ++i) acc[i] = 0.f;
    for (int k = 0; k < K; ++k) {
        float wk = W[k * HC + j];
#pragma unroll
        for (int i = 0; i < NPB; ++i) acc[i] += xs[i][k] * wk;
    }
    const int h = j >> 6, c = j & 63;
    const float ws = att_s[h * HID + c];
    const float wd = att_d[h * HID + c];
#pragma unroll
    for (int i = 0; i < NPB; ++i) {
        int n = n0 + i;
        float v = acc[i];
        hh[n * HC + j] = v;
        float rs = v * ws, rd = v * wd;
#pragma unroll
        for (int off = 32; off > 0; off >>= 1) {
            rs += __shfl_down(rs, off, 64);
            rd += __shfl_down(rd, off, 64);
        }
        if (c == 0) { a_src[n * HEADS + h] = rs; a_dst[n * HEADS + h] = rd; }
    }
}

// ================= CSR build (dst-sorted edge list) =================
__global__ void k_hist(const int* __restrict__ ei, int* __restrict__ counts) {
    int e = blockIdx.x * blockDim.x + threadIdx.x;
    if (e >= EP) return;
    int d = (e < N_EDGES) ? ei[N_EDGES + e] : (e - N_EDGES);
    atomicAdd(&counts[d], 1);
}

// single-block exclusive scan over counts -> row_ptr (+cursor copy)
__global__ void k_scan(const int* __restrict__ counts, int* __restrict__ row_ptr,
                       int* __restrict__ cursor) {
    __shared__ int buf[1024];
    __shared__ int carry;
    if (threadIdx.x == 0) carry = 0;
    __syncthreads();
    for (int base = 0; base < N_NODES; base += 1024) {
        int i = base + threadIdx.x;
        int v = (i < N_NODES) ? counts[i] : 0;
        buf[threadIdx.x] = v;
        __syncthreads();
        for (int off = 1; off < 1024; off <<= 1) {
            int t = (threadIdx.x >= off) ? buf[threadIdx.x - off] : 0;
            __syncthreads();
            buf[threadIdx.x] += t;
            __syncthreads();
        }
        int excl = buf[threadIdx.x] - v + carry;
        if (i < N_NODES) { row_ptr[i] = excl; cursor[i] = excl; }
        __syncthreads();
        if (threadIdx.x == 1023) carry += buf[1023];
        __syncthreads();
    }
    if (threadIdx.x == 0) row_ptr[N_NODES] = carry;   // == EP
}

__global__ void k_scatter(const int* __restrict__ ei, int* __restrict__ cursor,
                          int* __restrict__ esrc) {
    int e = blockIdx.x * blockDim.x + threadIdx.x;
    if (e >= EP) return;
    int s, d;
    if (e < N_EDGES) { s = ei[e]; d = ei[N_EDGES + e]; } else { s = d = e - N_EDGES; }
    int pos = atomicAdd(&cursor[d], 1);
    esrc[pos] = s;
}

// ===== fused GAT aggregate: softmax (shift-free) + weighted gather + ELU =====
// one 256-thread block per dst node; thread j owns output column j (head j>>6)
__global__ void k_gat_agg(const int* __restrict__ row_ptr, const int* __restrict__ esrc,
                          const float* __restrict__ hh, const float* __restrict__ a_src,
                          const float* __restrict__ a_dst, const float* __restrict__ bias,
                          float* __restrict__ out) {
    const int d = blockIdx.x;
    const int j = threadIdx.x;
    const int h = j >> 6;
    const float ad = a_dst[d * HEADS + h];
    const int beg = row_ptr[d], end = row_ptr[d + 1];
    float acc = 0.f, psum = 0.f;
    int s_next = esrc[beg];                       // every node has >= 1 (self-loop)
    for (int t = beg; t < end; ++t) {
        int s = s_next;
        if (t + 1 < end) s_next = esrc[t + 1];
        float e = a_src[s * HEADS + h] + ad;
        e = e > 0.f ? e : NEG_SLOPE * e;
        float p = __expf(e);
        psum += p;
        acc += p * hh[s * HC + j];
    }
    float v = acc / (psum + 1e-16f) + bias[j];
    out[d * HC + j] = v > 0.f ? v : (expf(v) - 1.f);
}

// ---- out proj + LayerNorm ----
template <int NPB>
__global__ void k_out_ln(const float* __restrict__ x, const float* __restrict__ W,
                         const float* __restrict__ b, const float* __restrict__ gamma,
                         const float* __restrict__ beta, float* __restrict__ out) {
    __shared__ float xs[NPB][HC];
    __shared__ float red[2][NPB][2];
    const int n0 = blockIdx.x * NPB;
    const int j = threadIdx.x;                 // 0..127
    for (int t = threadIdx.x; t < NPB * HC; t += 128) {
        int i = t >> 8, k = t & 255;
        xs[i][k] = x[(n0 + i) * HC + k];
    }
    __syncthreads();
    float acc[NPB];
#pragma unroll
    for (int i = 0; i < NPB; ++i) acc[i] = b[j];
    for (int k = 0; k < HC; ++k) {
        float wk = W[k * OUT_DIM + j];
#pragma unroll
        for (int i = 0; i < NPB; ++i) acc[i] += xs[i][k] * wk;
    }
    const int wave = j >> 6, lane = j & 63;
#pragma unroll
    for (int i = 0; i < NPB; ++i) {
        float s = acc[i], s2 = acc[i] * acc[i];
#pragma unroll
        for (int off = 32; off > 0; off >>= 1) {
            s += __shfl_down(s, off, 64);
            s2 += __shfl_down(s2, off, 64);
        }
        if (lane == 0) { red[wave][i][0] = s; red[wave][i][1] = s2; }
    }
    __syncthreads();
#pragma unroll
    for (int i = 0; i < NPB; ++i) {
        int n = n0 + i;
        float s = red[0][i][0] + red[1][i][0];
        float s2 = red[0][i][1] + red[1][i][1];
        float mu = s * (1.f / OUT_DIM);
        float var = s2 * (1.f / OUT_DIM) - mu * mu;
        float inv = rsqrtf(var + LN_EPS);
        out[n * OUT_DIM + j] = (acc[i] - mu) * inv * gamma[j] + beta[j];
    }
}

extern "C" void kernel_launch(void* const* d_in, const int* in_sizes, int n_in,
                              void* d_out, int out_size, void* d_ws, size_t ws_size,
                              hipStream_t stream) {
    const float* x        = (const float*)d_in[0];
    const int*   ei       = (const int*)  d_in[1];
    const float* W_in     = (const float*)d_in[2];
    const float* b_in     = (const float*)d_in[3];
    const float* lin0_w   = (const float*)d_in[4];
    const float* att0_src = (const float*)d_in[5];
    const float* att0_dst = (const float*)d_in[6];
    const float* bias0    = (const float*)d_in[7];
    const float* lin1_w   = (const float*)d_in[8];
    const float* att1_src = (const float*)d_in[9];
    const float* att1_dst = (const float*)d_in[10];
    const float* bias1    = (const float*)d_in[11];
    const float* W_out    = (const float*)d_in[12];
    const float* b_out    = (const float*)d_in[13];
    const float* ln_gamma = (const float*)d_in[14];
    const float* ln_beta  = (const float*)d_in[15];
    float* out = (float*)d_out;

    float* ws    = (float*)d_ws;
    float* h_in  = ws;                             // N*HID
    float* A     = h_in + (size_t)N_NODES * HID;   // N*HC
    float* B     = A + (size_t)N_NODES * HC;       // N*HC
    float* a_src = B + (size_t)N_NODES * HC;       // N*HEADS
    float* a_dst = a_src + (size_t)N_NODES * HEADS;
    int* counts  = (int*)(a_dst + (size_t)N_NODES * HEADS);  // N
    int* row_ptr = counts + N_NODES;               // N+1
    int* cursor  = row_ptr + N_NODES + 1;          // N
    int* esrc    = cursor + N_NODES;               // EP

    // 1. input projection
    k_in_proj<<<(N_NODES * HID) / 256, 256, 0, stream>>>(x, W_in, b_in, h_in);

    // 2. CSR build (once; shared by both GAT layers)
    hipMemsetAsync(counts, 0, N_NODES * sizeof(int), stream);
    k_hist<<<(EP + 255) / 256, 256, 0, stream>>>(ei, counts);
    k_scan<<<1, 1024, 0, stream>>>(counts, row_ptr, cursor);
    k_scatter<<<(EP + 255) / 256, 256, 0, stream>>>(ei, cursor, esrc);

    // ---- GAT layer 0 ----
    k_lin_att<HID, 8><<<N_NODES / 8, 256, 0, stream>>>(h_in, lin0_w, att0_src, att0_dst,
                                                       A, a_src, a_dst);
    k_gat_agg<<<N_NODES, 256, 0, stream>>>(row_ptr, esrc, A, a_src, a_dst, bias0, B);

    // ---- GAT layer 1 ----
    k_lin_att<HC, 8><<<N_NODES / 8, 256, 0, stream>>>(B, lin1_w, att1_src, att1_dst,
                                                      A, a_src, a_dst);
    k_gat_agg<<<N_NODES, 256, 0, stream>>>(row_ptr, esrc, A, a_src, a_dst, bias1, B);

    // ---- output projection + LayerNorm ----
    k_out_ln<4><<<N_NODES / 4, 128, 0, stream>>>(B, W_out, b_out, ln_gamma, ln_beta, out);
}

// Round 3
// 688.041 us; speedup vs baseline: 2.8174x; 1.4214x over previous
//
#include <hip/hip_runtime.h>
#include <cstdint>

#define N_NODES 50000
#define N_EDGES 800000
#define EP (N_EDGES + N_NODES)   // edges + self-loops
#define IN_DIM 32
#define HID 64
#define HEADS 4
#define HC 256                   // HID*HEADS
#define OUT_DIM 128
#define NEG_SLOPE 0.2f
#define LN_EPS 1e-5f
#define SCAN_B 1024
#define NB ((N_NODES + SCAN_B - 1) / SCAN_B)   // 49

// ---------------- input projection + ELU: h = elu(x @ W_in + b_in) ----------
__global__ void k_in_proj(const float* __restrict__ x, const float* __restrict__ W,
                          const float* __restrict__ b, float* __restrict__ out) {
    int g = blockIdx.x * blockDim.x + threadIdx.x;   // N*HID threads, exact
    int n = g >> 6, j = g & 63;
    const float* xr = x + n * IN_DIM;
    float acc = b[j];
#pragma unroll
    for (int k = 0; k < IN_DIM; ++k) acc += xr[k] * W[k * HID + j];
    out[g] = acc > 0.f ? acc : (__expf(acc) - 1.f);
}

// ==== lin + att dots: wave owns 16 nodes, lane owns 4 output cols =========
// block = 4 waves = 64 nodes; each ds_read_b128 of x feeds 16 FMAs (FMA-bound)
template <int K>
__global__ __launch_bounds__(256) void k_lin_att(
        const float* __restrict__ x, const float* __restrict__ W,
        const float* __restrict__ att_s, const float* __restrict__ att_d,
        float* __restrict__ hh, float* __restrict__ a_src, float* __restrict__ a_dst) {
    __shared__ float xs[64][K];
    const int n0 = blockIdx.x * 64;
    for (int t = threadIdx.x; t < (64 * K) / 4; t += 256) {
        int idx = t * 4;
        int i = idx / K, k = idx & (K - 1);
        int n = n0 + i;
        float4 v = {0.f, 0.f, 0.f, 0.f};
        if (n < N_NODES) v = *(const float4*)(x + (size_t)n * K + k);
        *(float4*)(&xs[i][k]) = v;
    }
    __syncthreads();
    const int wave = threadIdx.x >> 6;
    const int lane = threadIdx.x & 63;
    const int c0 = lane * 4;               // output col base
    const int iw = wave * 16;              // first node (in block) of this wave
    float4 acc[16];
#pragma unroll
    for (int i = 0; i < 16; ++i) acc[i] = {0.f, 0.f, 0.f, 0.f};
    for (int k = 0; k < K; k += 4) {
        float4 w0 = *(const float4*)(W + (size_t)(k + 0) * HC + c0);
        float4 w1 = *(const float4*)(W + (size_t)(k + 1) * HC + c0);
        float4 w2 = *(const float4*)(W + (size_t)(k + 2) * HC + c0);
        float4 w3 = *(const float4*)(W + (size_t)(k + 3) * HC + c0);
#pragma unroll
        for (int i = 0; i < 16; ++i) {
            float4 xv = *(const float4*)(&xs[iw + i][k]);
            acc[i].x += xv.x * w0.x; acc[i].y += xv.x * w0.y;
            acc[i].z += xv.x * w0.z; acc[i].w += xv.x * w0.w;
            acc[i].x += xv.y * w1.x; acc[i].y += xv.y * w1.y;
            acc[i].z += xv.y * w1.z; acc[i].w += xv.y * w1.w;
            acc[i].x += xv.z * w2.x; acc[i].y += xv.z * w2.y;
            acc[i].z += xv.z * w2.z; acc[i].w += xv.z * w2.w;
            acc[i].x += xv.w * w3.x; acc[i].y += xv.w * w3.y;
            acc[i].z += xv.w * w3.z; acc[i].w += xv.w * w3.w;
        }
    }
    // epilogue: write hh + attention dots (head = lane>>4, 16 lanes per head)
    const int h = lane >> 4;
    const float4 as4 = *(const float4*)(att_s + h * HID + (lane & 15) * 4);
    const float4 ad4 = *(const float4*)(att_d + h * HID + (lane & 15) * 4);
#pragma unroll
    for (int i = 0; i < 16; ++i) {
        int n = n0 + iw + i;
        if (n >= N_NODES) break;
        *(float4*)(hh + (size_t)n * HC + c0) = acc[i];
        float rs = acc[i].x * as4.x + acc[i].y * as4.y + acc[i].z * as4.z + acc[i].w * as4.w;
        float rd = acc[i].x * ad4.x + acc[i].y * ad4.y + acc[i].z * ad4.z + acc[i].w * ad4.w;
#pragma unroll
        for (int m = 1; m < 16; m <<= 1) {
            rs += __shfl_xor(rs, m, 64);
            rd += __shfl_xor(rd, m, 64);
        }
        if ((lane & 15) == 0) {
            a_src[n * HEADS + h] = rs;
            a_dst[n * HEADS + h] = rd;
        }
    }
}

// ================= CSR build (dst-sorted edge list) =================
__global__ void k_hist(const int* __restrict__ ei, int* __restrict__ counts) {
    int e = blockIdx.x * blockDim.x + threadIdx.x;
    if (e >= EP) return;
    int d = (e < N_EDGES) ? ei[N_EDGES + e] : (e - N_EDGES);
    atomicAdd(&counts[d], 1);
}

__global__ void k_scan1(const int* __restrict__ counts, int* __restrict__ chunk_excl,
                        int* __restrict__ bsum) {
    __shared__ int buf[SCAN_B];
    int i = blockIdx.x * SCAN_B + threadIdx.x;
    int v = (i < N_NODES) ? counts[i] : 0;
    buf[threadIdx.x] = v;
    __syncthreads();
    for (int off = 1; off < SCAN_B; off <<= 1) {
        int t = (threadIdx.x >= off) ? buf[threadIdx.x - off] : 0;
        __syncthreads();
        buf[threadIdx.x] += t;
        __syncthreads();
    }
    if (i < N_NODES) chunk_excl[i] = buf[threadIdx.x] - v;
    if (threadIdx.x == SCAN_B - 1) bsum[blockIdx.x] = buf[SCAN_B - 1];
}

__global__ void k_scan2(int* __restrict__ bsum) {   // exclusive scan of 49 sums
    int acc = 0;
    for (int b = 0; b < NB; ++b) { int t = bsum[b]; bsum[b] = acc; acc += t; }
}

__global__ void k_scan3(const int* __restrict__ chunk_excl, const int* __restrict__ bsum,
                        int* __restrict__ row_ptr, int* __restrict__ cursor) {
    int i = blockIdx.x * SCAN_B + threadIdx.x;
    if (i < N_NODES) {
        int v = chunk_excl[i] + bsum[blockIdx.x];
        row_ptr[i] = v;
        cursor[i] = v;
    }
    if (i == 0) row_ptr[N_NODES] = EP;
}

__global__ void k_scatter(const int* __restrict__ ei, int* __restrict__ cursor,
                          int* __restrict__ esrc) {
    int e = blockIdx.x * blockDim.x + threadIdx.x;
    if (e >= EP) return;
    int s, d;
    if (e < N_EDGES) { s = ei[e]; d = ei[N_EDGES + e]; } else { s = d = e - N_EDGES; }
    int pos = atomicAdd(&cursor[d], 1);
    esrc[pos] = s;
}

// ===== fused GAT aggregate: one wave per dst node, lane owns 4 cols =====
__global__ __launch_bounds__(256) void k_gat_agg(
        const int* __restrict__ row_ptr, const int* __restrict__ esrc,
        const float* __restrict__ hh, const float* __restrict__ a_src,
        const float* __restrict__ a_dst, const float* __restrict__ bias,
        float* __restrict__ out) {
    const int wave = threadIdx.x >> 6;
    const int lane = threadIdx.x & 63;
    const int d = blockIdx.x * 4 + wave;          // 50000 = 12500*4, exact
    const int h = lane >> 4;
    const int j = lane * 4;                        // contiguous: head h = j/64
    const float ad = a_dst[d * HEADS + h];
    const int beg = row_ptr[d], end = row_ptr[d + 1];
    float4 acc = {0.f, 0.f, 0.f, 0.f};
    float psum = 0.f;
    for (int base = beg; base < end; base += 64) {
        int cnt = end - base; if (cnt > 64) cnt = 64;
        int idx = base + lane;
        int myv = esrc[idx < end ? idx : end - 1];
        int i = 0;
        for (; i + 2 <= cnt; i += 2) {
            int s0 = __shfl(myv, i, 64);
            int s1 = __shfl(myv, i + 1, 64);
            float as0 = a_src[s0 * HEADS + h];
            float as1 = a_src[s1 * HEADS + h];
            float4 h0 = *(const float4*)(hh + (size_t)s0 * HC + j);
            float4 h1 = *(const float4*)(hh + (size_t)s1 * HC + j);
            float e0 = as0 + ad; e0 = e0 > 0.f ? e0 : NEG_SLOPE * e0;
            float e1 = as1 + ad; e1 = e1 > 0.f ? e1 : NEG_SLOPE * e1;
            float p0 = __expf(e0), p1 = __expf(e1);
            psum += p0 + p1;
            acc.x += p0 * h0.x + p1 * h1.x;
            acc.y += p0 * h0.y + p1 * h1.y;
            acc.z += p0 * h0.z + p1 * h1.z;
            acc.w += p0 * h0.w + p1 * h1.w;
        }
        if (i < cnt) {
            int s0 = __shfl(myv, i, 64);
            float as0 = a_src[s0 * HEADS + h];
            float4 h0 = *(const float4*)(hh + (size_t)s0 * HC + j);
            float e0 = as0 + ad; e0 = e0 > 0.f ? e0 : NEG_SLOPE * e0;
            float p0 = __expf(e0);
            psum += p0;
            acc.x += p0 * h0.x; acc.y += p0 * h0.y;
            acc.z += p0 * h0.z; acc.w += p0 * h0.w;
        }
    }
    const float inv = 1.f / (psum + 1e-16f);
    const float4 bb = *(const float4*)(bias + j);
    float4 v;
    v.x = acc.x * inv + bb.x; v.y = acc.y * inv + bb.y;
    v.z = acc.z * inv + bb.z; v.w = acc.w * inv + bb.w;
    v.x = v.x > 0.f ? v.x : (__expf(v.x) - 1.f);
    v.y = v.y > 0.f ? v.y : (__expf(v.y) - 1.f);
    v.z = v.z > 0.f ? v.z : (__expf(v.z) - 1.f);
    v.w = v.w > 0.f ? v.w : (__expf(v.w) - 1.f);
    *(float4*)(out + (size_t)d * HC + j) = v;
}

// ==== out proj + LayerNorm: wave owns 16 nodes, lane owns 2 cols ====
__global__ __launch_bounds__(256) void k_out_ln(
        const float* __restrict__ x, const float* __restrict__ W,
        const float* __restrict__ b, const float* __restrict__ gamma,
        const float* __restrict__ beta, float* __restrict__ out) {
    __shared__ float xs[64][HC];
    const int n0 = blockIdx.x * 64;
    for (int t = threadIdx.x; t < (64 * HC) / 4; t += 256) {
        int idx = t * 4;
        int i = idx >> 8, k = idx & 255;
        int n = n0 + i;
        float4 v = {0.f, 0.f, 0.f, 0.f};
        if (n < N_NODES) v = *(const float4*)(x + (size_t)n * HC + k);
        *(float4*)(&xs[i][k]) = v;
    }
    __syncthreads();
    const int wave = threadIdx.x >> 6;
    const int lane = threadIdx.x & 63;
    const int c0 = lane * 2;               // output col base (0..126)
    const int iw = wave * 16;
    float2 acc[16];
#pragma unroll
    for (int i = 0; i < 16; ++i) acc[i] = {0.f, 0.f};
    for (int k = 0; k < HC; k += 4) {
        float2 w0 = *(const float2*)(W + (size_t)(k + 0) * OUT_DIM + c0);
        float2 w1 = *(const float2*)(W + (size_t)(k + 1) * OUT_DIM + c0);
        float2 w2 = *(const float2*)(W + (size_t)(k + 2) * OUT_DIM + c0);
        float2 w3 = *(const float2*)(W + (size_t)(k + 3) * OUT_DIM + c0);
#pragma unroll
        for (int i = 0; i < 16; ++i) {
            float4 xv = *(const float4*)(&xs[iw + i][k]);
            acc[i].x += xv.x * w0.x; acc[i].y += xv.x * w0.y;
            acc[i].x += xv.y * w1.x; acc[i].y += xv.y * w1.y;
            acc[i].x += xv.z * w2.x; acc[i].y += xv.z * w2.y;
            acc[i].x += xv.w * w3.x; acc[i].y += xv.w * w3.y;
        }
    }
    const float2 bb = *(const float2*)(b + c0);
    const float2 gg = *(const float2*)(gamma + c0);
    const float2 be = *(const float2*)(beta + c0);
#pragma unroll
    for (int i = 0; i < 16; ++i) {
        int n = n0 + iw + i;
        if (n >= N_NODES) break;
        float ax = acc[i].x + bb.x, ay = acc[i].y + bb.y;
        float s = ax + ay, s2 = ax * ax + ay * ay;
#pragma unroll
        for (int m = 1; m < 64; m <<= 1) {
            s += __shfl_xor(s, m, 64);
            s2 += __shfl_xor(s2, m, 64);
        }
        float mu = s * (1.f / OUT_DIM);
        float var = s2 * (1.f / OUT_DIM) - mu * mu;
        float inv = rsqrtf(var + LN_EPS);
        float2 o;
        o.x = (ax - mu) * inv * gg.x + be.x;
        o.y = (ay - mu) * inv * gg.y + be.y;
        *(float2*)(out + (size_t)n * OUT_DIM + c0) = o;
    }
}

extern "C" void kernel_launch(void* const* d_in, const int* in_sizes, int n_in,
                              void* d_out, int out_size, void* d_ws, size_t ws_size,
                              hipStream_t stream) {
    const float* x        = (const float*)d_in[0];
    const int*   ei       = (const int*)  d_in[1];
    const float* W_in     = (const float*)d_in[2];
    const float* b_in     = (const float*)d_in[3];
    const float* lin0_w   = (const float*)d_in[4];
    const float* att0_src = (const float*)d_in[5];
    const float* att0_dst = (const float*)d_in[6];
    const float* bias0    = (const float*)d_in[7];
    const float* lin1_w   = (const float*)d_in[8];
    const float* att1_src = (const float*)d_in[9];
    const float* att1_dst = (const float*)d_in[10];
    const float* bias1    = (const float*)d_in[11];
    const float* W_out    = (const float*)d_in[12];
    const float* b_out    = (const float*)d_in[13];
    const float* ln_gamma = (const float*)d_in[14];
    const float* ln_beta  = (const float*)d_in[15];
    float* out = (float*)d_out;

    float* ws    = (float*)d_ws;
    float* h_in  = ws;                             // N*HID
    float* A     = h_in + (size_t)N_NODES * HID;   // N*HC
    float* B     = A + (size_t)N_NODES * HC;       // N*HC
    float* a_src = B + (size_t)N_NODES * HC;       // N*HEADS
    float* a_dst = a_src + (size_t)N_NODES * HEADS;
    int* counts     = (int*)(a_dst + (size_t)N_NODES * HEADS);  // N
    int* chunk_excl = counts + N_NODES;            // N
    int* bsum       = chunk_excl + N_NODES;        // NB
    int* row_ptr    = bsum + NB;                   // N+1
    int* cursor     = row_ptr + N_NODES + 1;       // N
    int* esrc       = cursor + N_NODES;            // EP

    // 1. input projection
    k_in_proj<<<(N_NODES * HID) / 256, 256, 0, stream>>>(x, W_in, b_in, h_in);

    // 2. CSR build (once; shared by both GAT layers)
    hipMemsetAsync(counts, 0, N_NODES * sizeof(int), stream);
    k_hist<<<(EP + 255) / 256, 256, 0, stream>>>(ei, counts);
    k_scan1<<<NB, SCAN_B, 0, stream>>>(counts, chunk_excl, bsum);
    k_scan2<<<1, 1, 0, stream>>>(bsum);
    k_scan3<<<NB, SCAN_B, 0, stream>>>(chunk_excl, bsum, row_ptr, cursor);
    k_scatter<<<(EP + 255) / 256, 256, 0, stream>>>(ei, cursor, esrc);

    const int gemm_grid = (N_NODES + 63) / 64;     // 782

    // ---- GAT layer 0 ----
    k_lin_att<HID><<<gemm_grid, 256, 0, stream>>>(h_in, lin0_w, att0_src, att0_dst,
                                                  A, a_src, a_dst);
    k_gat_agg<<<N_NODES / 4, 256, 0, stream>>>(row_ptr, esrc, A, a_src, a_dst, bias0, B);

    // ---- GAT layer 1 ----
    k_lin_att<HC><<<gemm_grid, 256, 0, stream>>>(B, lin1_w, att1_src, att1_dst,
                                                 A, a_src, a_dst);
    k_gat_agg<<<N_NODES / 4, 256, 0, stream>>>(row_ptr, esrc, A, a_src, a_dst, bias1, B);

    // ---- output projection + LayerNorm ----
    k_out_ln<<<gemm_grid, 256, 0, stream>>>(B, W_out, b_out, ln_gamma, ln_beta, out);
}

// Round 4
// 565.676 us; speedup vs baseline: 3.4269x; 1.2163x over previous
//
#include <hip/hip_runtime.h>
#include <cstdint>

#define N_NODES 50000
#define N_EDGES 800000
#define EP (N_EDGES + N_NODES)   // edges + self-loops
#define IN_DIM 32
#define HID 64
#define HEADS 4
#define HC 256                   // HID*HEADS
#define OUT_DIM 128
#define NEG_SLOPE 0.2f
#define LN_EPS 1e-5f
#define SCAN_B 1024
#define NB ((N_NODES + SCAN_B - 1) / SCAN_B)   // 49

__device__ __forceinline__ unsigned bf16rne(float f) {
    unsigned u = __float_as_uint(f);
    return (u + 0x7fffu + ((u >> 16) & 1u)) >> 16;
}
__device__ __forceinline__ unsigned pack_bf2(float a, float b) {
    return bf16rne(a) | (bf16rne(b) << 16);
}

// ---------------- input projection + ELU: h = elu(x @ W_in + b_in) ----------
__global__ void k_in_proj(const float* __restrict__ x, const float* __restrict__ W,
                          const float* __restrict__ b, float* __restrict__ out) {
    int g = blockIdx.x * blockDim.x + threadIdx.x;   // N*HID threads, exact
    int n = g >> 6, j = g & 63;
    const float* xr = x + n * IN_DIM;
    float acc = b[j];
#pragma unroll
    for (int k = 0; k < IN_DIM; ++k) acc += xr[k] * W[k * HID + j];
    out[g] = acc > 0.f ? acc : (__expf(acc) - 1.f);
}

// ==== lin + att dots: wave owns 16 nodes, lane owns 4 output cols =========
// hh is written as bf16 (consumed only by the gather-bound aggregate kernel)
template <int K>
__global__ __launch_bounds__(256) void k_lin_att(
        const float* __restrict__ x, const float* __restrict__ W,
        const float* __restrict__ att_s, const float* __restrict__ att_d,
        unsigned short* __restrict__ hh, float* __restrict__ a_src,
        float* __restrict__ a_dst) {
    __shared__ float xs[64][K];
    const int n0 = blockIdx.x * 64;
    for (int t = threadIdx.x; t < (64 * K) / 4; t += 256) {
        int idx = t * 4;
        int i = idx / K, k = idx & (K - 1);
        int n = n0 + i;
        float4 v = {0.f, 0.f, 0.f, 0.f};
        if (n < N_NODES) v = *(const float4*)(x + (size_t)n * K + k);
        *(float4*)(&xs[i][k]) = v;
    }
    __syncthreads();
    const int wave = threadIdx.x >> 6;
    const int lane = threadIdx.x & 63;
    const int c0 = lane * 4;               // output col base
    const int iw = wave * 16;              // first node (in block) of this wave
    float4 acc[16];
#pragma unroll
    for (int i = 0; i < 16; ++i) acc[i] = {0.f, 0.f, 0.f, 0.f};
    for (int k = 0; k < K; k += 4) {
        float4 w0 = *(const float4*)(W + (size_t)(k + 0) * HC + c0);
        float4 w1 = *(const float4*)(W + (size_t)(k + 1) * HC + c0);
        float4 w2 = *(const float4*)(W + (size_t)(k + 2) * HC + c0);
        float4 w3 = *(const float4*)(W + (size_t)(k + 3) * HC + c0);
#pragma unroll
        for (int i = 0; i < 16; ++i) {
            float4 xv = *(const float4*)(&xs[iw + i][k]);
            acc[i].x += xv.x * w0.x; acc[i].y += xv.x * w0.y;
            acc[i].z += xv.x * w0.z; acc[i].w += xv.x * w0.w;
            acc[i].x += xv.y * w1.x; acc[i].y += xv.y * w1.y;
            acc[i].z += xv.y * w1.z; acc[i].w += xv.y * w1.w;
            acc[i].x += xv.z * w2.x; acc[i].y += xv.z * w2.y;
            acc[i].z += xv.z * w2.z; acc[i].w += xv.z * w2.w;
            acc[i].x += xv.w * w3.x; acc[i].y += xv.w * w3.y;
            acc[i].z += xv.w * w3.z; acc[i].w += xv.w * w3.w;
        }
    }
    // epilogue: write hh (bf16) + attention dots (head = lane>>4)
    const int h = lane >> 4;
    const float4 as4 = *(const float4*)(att_s + h * HID + (lane & 15) * 4);
    const float4 ad4 = *(const float4*)(att_d + h * HID + (lane & 15) * 4);
#pragma unroll
    for (int i = 0; i < 16; ++i) {
        int n = n0 + iw + i;
        if (n >= N_NODES) break;
        uint2 pk;
        pk.x = pack_bf2(acc[i].x, acc[i].y);
        pk.y = pack_bf2(acc[i].z, acc[i].w);
        *(uint2*)(hh + (size_t)n * HC + c0) = pk;
        float rs = acc[i].x * as4.x + acc[i].y * as4.y + acc[i].z * as4.z + acc[i].w * as4.w;
        float rd = acc[i].x * ad4.x + acc[i].y * ad4.y + acc[i].z * ad4.z + acc[i].w * ad4.w;
#pragma unroll
        for (int m = 1; m < 16; m <<= 1) {
            rs += __shfl_xor(rs, m, 64);
            rd += __shfl_xor(rd, m, 64);
        }
        if ((lane & 15) == 0) {
            a_src[n * HEADS + h] = rs;
            a_dst[n * HEADS + h] = rd;
        }
    }
}

// ================= CSR build (dst-sorted edge list) =================
__global__ void k_hist(const int* __restrict__ ei, int* __restrict__ counts) {
    int e = blockIdx.x * blockDim.x + threadIdx.x;
    if (e >= EP) return;
    int d = (e < N_EDGES) ? ei[N_EDGES + e] : (e - N_EDGES);
    atomicAdd(&counts[d], 1);
}

__global__ void k_scan1(const int* __restrict__ counts, int* __restrict__ chunk_excl,
                        int* __restrict__ bsum) {
    __shared__ int buf[SCAN_B];
    int i = blockIdx.x * SCAN_B + threadIdx.x;
    int v = (i < N_NODES) ? counts[i] : 0;
    buf[threadIdx.x] = v;
    __syncthreads();
    for (int off = 1; off < SCAN_B; off <<= 1) {
        int t = (threadIdx.x >= off) ? buf[threadIdx.x - off] : 0;
        __syncthreads();
        buf[threadIdx.x] += t;
        __syncthreads();
    }
    if (i < N_NODES) chunk_excl[i] = buf[threadIdx.x] - v;
    if (threadIdx.x == SCAN_B - 1) bsum[blockIdx.x] = buf[SCAN_B - 1];
}

__global__ void k_scan2(int* __restrict__ bsum) {   // exclusive scan of 49 sums
    int acc = 0;
    for (int b = 0; b < NB; ++b) { int t = bsum[b]; bsum[b] = acc; acc += t; }
}

__global__ void k_scan3(const int* __restrict__ chunk_excl, const int* __restrict__ bsum,
                        int* __restrict__ row_ptr, int* __restrict__ cursor) {
    int i = blockIdx.x * SCAN_B + threadIdx.x;
    if (i < N_NODES) {
        int v = chunk_excl[i] + bsum[blockIdx.x];
        row_ptr[i] = v;
        cursor[i] = v;
    }
    if (i == 0) row_ptr[N_NODES] = EP;
}

__global__ void k_scatter(const int* __restrict__ ei, int* __restrict__ cursor,
                          int* __restrict__ esrc) {
    int e = blockIdx.x * blockDim.x + threadIdx.x;
    if (e >= EP) return;
    int s, d;
    if (e < N_EDGES) { s = ei[e]; d = ei[N_EDGES + e]; } else { s = d = e - N_EDGES; }
    int pos = atomicAdd(&cursor[d], 1);
    esrc[pos] = s;
}

// ===== fused GAT aggregate: one wave per dst node, lane owns 4 cols (bf16 hh) =====
__global__ __launch_bounds__(256) void k_gat_agg(
        const int* __restrict__ row_ptr, const int* __restrict__ esrc,
        const unsigned short* __restrict__ hh, const float* __restrict__ a_src,
        const float* __restrict__ a_dst, const float* __restrict__ bias,
        float* __restrict__ out) {
    const int wave = threadIdx.x >> 6;
    const int lane = threadIdx.x & 63;
    const int d = blockIdx.x * 4 + wave;          // 50000 = 12500*4, exact
    const int h = lane >> 4;
    const int j = lane * 4;                        // contiguous: head h = j/64
    const float ad = a_dst[d * HEADS + h];
    const int beg = row_ptr[d], end = row_ptr[d + 1];
    float4 acc = {0.f, 0.f, 0.f, 0.f};
    float psum = 0.f;
    for (int base = beg; base < end; base += 64) {
        int cnt = end - base; if (cnt > 64) cnt = 64;
        int idx = base + lane;
        int myv = esrc[idx < end ? idx : end - 1];
        int i = 0;
        for (; i + 2 <= cnt; i += 2) {
            int s0 = __shfl(myv, i, 64);
            int s1 = __shfl(myv, i + 1, 64);
            float as0 = a_src[s0 * HEADS + h];
            float as1 = a_src[s1 * HEADS + h];
            uint2 g0 = *(const uint2*)(hh + (size_t)s0 * HC + j);
            uint2 g1 = *(const uint2*)(hh + (size_t)s1 * HC + j);
            float e0 = as0 + ad; e0 = e0 > 0.f ? e0 : NEG_SLOPE * e0;
            float e1 = as1 + ad; e1 = e1 > 0.f ? e1 : NEG_SLOPE * e1;
            float p0 = __expf(e0), p1 = __expf(e1);
            psum += p0 + p1;
            acc.x += p0 * __uint_as_float(g0.x << 16) + p1 * __uint_as_float(g1.x << 16);
            acc.y += p0 * __uint_as_float(g0.x & 0xffff0000u) + p1 * __uint_as_float(g1.x & 0xffff0000u);
            acc.z += p0 * __uint_as_float(g0.y << 16) + p1 * __uint_as_float(g1.y << 16);
            acc.w += p0 * __uint_as_float(g0.y & 0xffff0000u) + p1 * __uint_as_float(g1.y & 0xffff0000u);
        }
        if (i < cnt) {
            int s0 = __shfl(myv, i, 64);
            float as0 = a_src[s0 * HEADS + h];
            uint2 g0 = *(const uint2*)(hh + (size_t)s0 * HC + j);
            float e0 = as0 + ad; e0 = e0 > 0.f ? e0 : NEG_SLOPE * e0;
            float p0 = __expf(e0);
            psum += p0;
            acc.x += p0 * __uint_as_float(g0.x << 16);
            acc.y += p0 * __uint_as_float(g0.x & 0xffff0000u);
            acc.z += p0 * __uint_as_float(g0.y << 16);
            acc.w += p0 * __uint_as_float(g0.y & 0xffff0000u);
        }
    }
    const float inv = 1.f / (psum + 1e-16f);
    const float4 bb = *(const float4*)(bias + j);
    float4 v;
    v.x = acc.x * inv + bb.x; v.y = acc.y * inv + bb.y;
    v.z = acc.z * inv + bb.z; v.w = acc.w * inv + bb.w;
    v.x = v.x > 0.f ? v.x : (__expf(v.x) - 1.f);
    v.y = v.y > 0.f ? v.y : (__expf(v.y) - 1.f);
    v.z = v.z > 0.f ? v.z : (__expf(v.z) - 1.f);
    v.w = v.w > 0.f ? v.w : (__expf(v.w) - 1.f);
    *(float4*)(out + (size_t)d * HC + j) = v;
}

// ==== out proj + LayerNorm: wave owns 16 nodes, lane owns 2 cols ====
__global__ __launch_bounds__(256) void k_out_ln(
        const float* __restrict__ x, const float* __restrict__ W,
        const float* __restrict__ b, const float* __restrict__ gamma,
        const float* __restrict__ beta, float* __restrict__ out) {
    __shared__ float xs[64][HC];
    const int n0 = blockIdx.x * 64;
    for (int t = threadIdx.x; t < (64 * HC) / 4; t += 256) {
        int idx = t * 4;
        int i = idx >> 8, k = idx & 255;
        int n = n0 + i;
        float4 v = {0.f, 0.f, 0.f, 0.f};
        if (n < N_NODES) v = *(const float4*)(x + (size_t)n * HC + k);
        *(float4*)(&xs[i][k]) = v;
    }
    __syncthreads();
    const int wave = threadIdx.x >> 6;
    const int lane = threadIdx.x & 63;
    const int c0 = lane * 2;               // output col base (0..126)
    const int iw = wave * 16;
    float2 acc[16];
#pragma unroll
    for (int i = 0; i < 16; ++i) acc[i] = {0.f, 0.f};
    for (int k = 0; k < HC; k += 4) {
        float2 w0 = *(const float2*)(W + (size_t)(k + 0) * OUT_DIM + c0);
        float2 w1 = *(const float2*)(W + (size_t)(k + 1) * OUT_DIM + c0);
        float2 w2 = *(const float2*)(W + (size_t)(k + 2) * OUT_DIM + c0);
        float2 w3 = *(const float2*)(W + (size_t)(k + 3) * OUT_DIM + c0);
#pragma unroll
        for (int i = 0; i < 16; ++i) {
            float4 xv = *(const float4*)(&xs[iw + i][k]);
            acc[i].x += xv.x * w0.x; acc[i].y += xv.x * w0.y;
            acc[i].x += xv.y * w1.x; acc[i].y += xv.y * w1.y;
            acc[i].x += xv.z * w2.x; acc[i].y += xv.z * w2.y;
            acc[i].x += xv.w * w3.x; acc[i].y += xv.w * w3.y;
        }
    }
    const float2 bb = *(const float2*)(b + c0);
    const float2 gg = *(const float2*)(gamma + c0);
    const float2 be = *(const float2*)(beta + c0);
#pragma unroll
    for (int i = 0; i < 16; ++i) {
        int n = n0 + iw + i;
        if (n >= N_NODES) break;
        float ax = acc[i].x + bb.x, ay = acc[i].y + bb.y;
        float s = ax + ay, s2 = ax * ax + ay * ay;
#pragma unroll
        for (int m = 1; m < 64; m <<= 1) {
            s += __shfl_xor(s, m, 64);
            s2 += __shfl_xor(s2, m, 64);
        }
        float mu = s * (1.f / OUT_DIM);
        float var = s2 * (1.f / OUT_DIM) - mu * mu;
        float inv = rsqrtf(var + LN_EPS);
        float2 o;
        o.x = (ax - mu) * inv * gg.x + be.x;
        o.y = (ay - mu) * inv * gg.y + be.y;
        *(float2*)(out + (size_t)n * OUT_DIM + c0) = o;
    }
}

extern "C" void kernel_launch(void* const* d_in, const int* in_sizes, int n_in,
                              void* d_out, int out_size, void* d_ws, size_t ws_size,
                              hipStream_t stream) {
    const float* x        = (const float*)d_in[0];
    const int*   ei       = (const int*)  d_in[1];
    const float* W_in     = (const float*)d_in[2];
    const float* b_in     = (const float*)d_in[3];
    const float* lin0_w   = (const float*)d_in[4];
    const float* att0_src = (const float*)d_in[5];
    const float* att0_dst = (const float*)d_in[6];
    const float* bias0    = (const float*)d_in[7];
    const float* lin1_w   = (const float*)d_in[8];
    const float* att1_src = (const float*)d_in[9];
    const float* att1_dst = (const float*)d_in[10];
    const float* bias1    = (const float*)d_in[11];
    const float* W_out    = (const float*)d_in[12];
    const float* b_out    = (const float*)d_in[13];
    const float* ln_gamma = (const float*)d_in[14];
    const float* ln_beta  = (const float*)d_in[15];
    float* out = (float*)d_out;

    float* ws    = (float*)d_ws;
    float* h_in  = ws;                             // N*HID f32
    float* featA = h_in + (size_t)N_NODES * HID;   // N*HC f32
    float* featB = featA + (size_t)N_NODES * HC;   // N*HC f32
    float* a_src = featB + (size_t)N_NODES * HC;   // N*HEADS
    float* a_dst = a_src + (size_t)N_NODES * HEADS;
    unsigned short* hh_bf = (unsigned short*)(a_dst + (size_t)N_NODES * HEADS); // N*HC bf16
    int* counts     = (int*)(hh_bf + (size_t)N_NODES * HC);  // N
    int* chunk_excl = counts + N_NODES;            // N
    int* bsum       = chunk_excl + N_NODES;        // NB
    int* row_ptr    = bsum + NB;                   // N+1
    int* cursor     = row_ptr + N_NODES + 1;       // N
    int* esrc       = cursor + N_NODES;            // EP

    // 1. input projection
    k_in_proj<<<(N_NODES * HID) / 256, 256, 0, stream>>>(x, W_in, b_in, h_in);

    // 2. CSR build (once; shared by both GAT layers)
    hipMemsetAsync(counts, 0, N_NODES * sizeof(int), stream);
    k_hist<<<(EP + 255) / 256, 256, 0, stream>>>(ei, counts);
    k_scan1<<<NB, SCAN_B, 0, stream>>>(counts, chunk_excl, bsum);
    k_scan2<<<1, 1, 0, stream>>>(bsum);
    k_scan3<<<NB, SCAN_B, 0, stream>>>(chunk_excl, bsum, row_ptr, cursor);
    k_scatter<<<(EP + 255) / 256, 256, 0, stream>>>(ei, cursor, esrc);

    const int gemm_grid = (N_NODES + 63) / 64;     // 782

    // ---- GAT layer 0 ----
    k_lin_att<HID><<<gemm_grid, 256, 0, stream>>>(h_in, lin0_w, att0_src, att0_dst,
                                                  hh_bf, a_src, a_dst);
    k_gat_agg<<<N_NODES / 4, 256, 0, stream>>>(row_ptr, esrc, hh_bf, a_src, a_dst,
                                               bias0, featA);

    // ---- GAT layer 1 ----
    k_lin_att<HC><<<gemm_grid, 256, 0, stream>>>(featA, lin1_w, att1_src, att1_dst,
                                                 hh_bf, a_src, a_dst);
    k_gat_agg<<<N_NODES / 4, 256, 0, stream>>>(row_ptr, esrc, hh_bf, a_src, a_dst,
                                               bias1, featB);

    // ---- output projection + LayerNorm ----
    k_out_ln<<<gemm_grid, 256, 0, stream>>>(featB, W_out, b_out, ln_gamma, ln_beta, out);
}

// Round 5
// 432.537 us; speedup vs baseline: 4.4817x; 1.3078x over previous
//
#include <hip/hip_runtime.h>
#include <cstdint>

#define N_NODES 50000
#define N_EDGES 800000
#define EP (N_EDGES + N_NODES)   // edges + self-loops
#define IN_DIM 32
#define HID 64
#define HEADS 4
#define HC 256                   // HID*HEADS
#define OUT_DIM 128
#define NEG_SLOPE 0.2f
#define LN_EPS 1e-5f
#define SCAN_B 1024
#define NB ((N_NODES + SCAN_B - 1) / SCAN_B)   // 49

typedef __attribute__((ext_vector_type(8))) short bf16x8;
typedef __attribute__((ext_vector_type(16))) float f32x16;

__device__ __forceinline__ unsigned bf16rne(float f) {
    unsigned u = __float_as_uint(f);
    return (u + 0x7fffu + ((u >> 16) & 1u)) >> 16;
}
__device__ __forceinline__ unsigned pack_bf2(float a, float b) {
    return bf16rne(a) | (bf16rne(b) << 16);
}

// ------- input projection + ELU: h = elu(x @ W_in + b_in), bf16 out -------
__global__ void k_in_proj(const float* __restrict__ x, const float* __restrict__ W,
                          const float* __restrict__ b, unsigned short* __restrict__ out) {
    int g = blockIdx.x * blockDim.x + threadIdx.x;   // N*HID threads, exact
    int n = g >> 6, j = g & 63;
    const float* xr = x + n * IN_DIM;
    float acc = b[j];
#pragma unroll
    for (int k = 0; k < IN_DIM; ++k) acc += xr[k] * W[k * HID + j];
    acc = acc > 0.f ? acc : (__expf(acc) - 1.f);
    out[g] = (unsigned short)bf16rne(acc);
}

// ------- pack the three weight matrices to bf16 [K/8][N][8] -------
__global__ void k_wpack(const float* __restrict__ w0, const float* __restrict__ w1,
                        const float* __restrict__ w2, unsigned short* __restrict__ p0,
                        unsigned short* __restrict__ p1, unsigned short* __restrict__ p2) {
    int g = blockIdx.x * blockDim.x + threadIdx.x;
    if (g < HID * HC) {                      // lin0_w: 64x256
        int k = g >> 8, n = g & 255;
        p0[(((k >> 3) * HC) + n) * 8 + (k & 7)] = (unsigned short)bf16rne(w0[g]);
    } else if (g < HID * HC + HC * HC) {     // lin1_w: 256x256
        int t = g - HID * HC;
        int k = t >> 8, n = t & 255;
        p1[(((k >> 3) * HC) + n) * 8 + (k & 7)] = (unsigned short)bf16rne(w1[t]);
    } else if (g < HID * HC + HC * HC + HC * OUT_DIM) {   // W_out: 256x128
        int t = g - HID * HC - HC * HC;
        int k = t >> 7, n = t & 127;
        p2[(((k >> 3) * OUT_DIM) + n) * 8 + (k & 7)] = (unsigned short)bf16rne(w2[t]);
    }
}

// ======= MFMA GEMM: hh[M,256] = A[M,K] @ B[K,256]  (bf16 in, bf16 out) =======
// block = 4 waves; wave computes 32 rows x 256 cols with 8 32x32x16 tiles
template <int K>
__global__ __launch_bounds__(256) void k_gemm_lin(
        const unsigned short* __restrict__ A, const unsigned short* __restrict__ Bp,
        unsigned short* __restrict__ hh) {
    const int lane = threadIdx.x & 63;
    const int quad = lane >> 5, c = lane & 31;
    const int m0 = blockIdx.x * 128 + (threadIdx.x >> 6) * 32;
    f32x16 acc[8];
#pragma unroll
    for (int nt = 0; nt < 8; ++nt)
#pragma unroll
        for (int i = 0; i < 16; ++i) acc[nt][i] = 0.f;
    int mrow = m0 + c; if (mrow >= N_NODES) mrow = N_NODES - 1;
    const size_t abase = (size_t)mrow * K + quad * 8;
    for (int k0 = 0; k0 < K; k0 += 16) {
        bf16x8 af = *(const bf16x8*)(A + abase + k0);
        const unsigned short* bk = Bp + ((size_t)(k0 >> 3) + quad) * (HC * 8);
#pragma unroll
        for (int nt = 0; nt < 8; ++nt) {
            bf16x8 bf = *(const bf16x8*)(bk + (nt * 32 + c) * 8);
            acc[nt] = __builtin_amdgcn_mfma_f32_32x32x16_bf16(af, bf, acc[nt], 0, 0, 0);
        }
    }
#pragma unroll
    for (int reg = 0; reg < 16; ++reg) {
        int row = (reg & 3) + 8 * (reg >> 2) + 4 * quad;
        int m = m0 + row;
        if (m < N_NODES) {
            size_t base = (size_t)m * HC + c;
#pragma unroll
            for (int nt = 0; nt < 8; ++nt)
                hh[base + nt * 32] = (unsigned short)bf16rne(acc[nt][reg]);
        }
    }
}

// ------- attention dots from bf16 hh: a_src[n,h]=<hh[n,h,:],att_s[h,:]> -------
// wave handles 2 nodes (32 lanes/node, 8 cols/lane)
__global__ void k_att_dots(const unsigned short* __restrict__ hh,
                           const float* __restrict__ att_s, const float* __restrict__ att_d,
                           float* __restrict__ a_src, float* __restrict__ a_dst) {
    int wid = (blockIdx.x * blockDim.x + threadIdx.x) >> 6;
    int lane = threadIdx.x & 63;
    int node = wid * 2 + (lane >> 5);          // 50000 even: exact
    int c0 = (lane & 31) * 8;
    int h = (lane & 31) >> 3;                  // head = c0/64
    uint4 raw = *(const uint4*)(hh + (size_t)node * HC + c0);
    float as = 0.f, ad = 0.f;
#pragma unroll
    for (int t = 0; t < 4; ++t) {
        unsigned w = ((const unsigned*)&raw)[t];
        float v0 = __uint_as_float(w << 16);
        float v1 = __uint_as_float(w & 0xffff0000u);
        int cc = (c0 & 63) + t * 2;
        as += v0 * att_s[h * HID + cc] + v1 * att_s[h * HID + cc + 1];
        ad += v0 * att_d[h * HID + cc] + v1 * att_d[h * HID + cc + 1];
    }
#pragma unroll
    for (int m = 1; m < 8; m <<= 1) {
        as += __shfl_xor(as, m, 64);
        ad += __shfl_xor(ad, m, 64);
    }
    if ((lane & 7) == 0) {
        a_src[node * HEADS + h] = as;
        a_dst[node * HEADS + h] = ad;
    }
}

// ================= CSR build (dst-sorted edge list) =================
__global__ void k_hist(const int* __restrict__ ei, int* __restrict__ counts) {
    int e = blockIdx.x * blockDim.x + threadIdx.x;
    if (e >= EP) return;
    int d = (e < N_EDGES) ? ei[N_EDGES + e] : (e - N_EDGES);
    atomicAdd(&counts[d], 1);
}

__global__ void k_scan1(const int* __restrict__ counts, int* __restrict__ chunk_excl,
                        int* __restrict__ bsum) {
    __shared__ int buf[SCAN_B];
    int i = blockIdx.x * SCAN_B + threadIdx.x;
    int v = (i < N_NODES) ? counts[i] : 0;
    buf[threadIdx.x] = v;
    __syncthreads();
    for (int off = 1; off < SCAN_B; off <<= 1) {
        int t = (threadIdx.x >= off) ? buf[threadIdx.x - off] : 0;
        __syncthreads();
        buf[threadIdx.x] += t;
        __syncthreads();
    }
    if (i < N_NODES) chunk_excl[i] = buf[threadIdx.x] - v;
    if (threadIdx.x == SCAN_B - 1) bsum[blockIdx.x] = buf[SCAN_B - 1];
}

__global__ void k_scan2(int* __restrict__ bsum) {
    int acc = 0;
    for (int b = 0; b < NB; ++b) { int t = bsum[b]; bsum[b] = acc; acc += t; }
}

__global__ void k_scan3(const int* __restrict__ chunk_excl, const int* __restrict__ bsum,
                        int* __restrict__ row_ptr, int* __restrict__ cursor) {
    int i = blockIdx.x * SCAN_B + threadIdx.x;
    if (i < N_NODES) {
        int v = chunk_excl[i] + bsum[blockIdx.x];
        row_ptr[i] = v;
        cursor[i] = v;
    }
    if (i == 0) row_ptr[N_NODES] = EP;
}

__global__ void k_scatter(const int* __restrict__ ei, int* __restrict__ cursor,
                          int* __restrict__ esrc) {
    int e = blockIdx.x * blockDim.x + threadIdx.x;
    if (e >= EP) return;
    int s, d;
    if (e < N_EDGES) { s = ei[e]; d = ei[N_EDGES + e]; } else { s = d = e - N_EDGES; }
    int pos = atomicAdd(&cursor[d], 1);
    esrc[pos] = s;
}

// ===== fused GAT aggregate: one wave per dst node, lane owns 4 cols; bf16 out =====
__global__ __launch_bounds__(256) void k_gat_agg(
        const int* __restrict__ row_ptr, const int* __restrict__ esrc,
        const unsigned short* __restrict__ hh, const float* __restrict__ a_src,
        const float* __restrict__ a_dst, const float* __restrict__ bias,
        unsigned short* __restrict__ out) {
    const int wave = threadIdx.x >> 6;
    const int lane = threadIdx.x & 63;
    const int d = blockIdx.x * 4 + wave;          // 50000 = 12500*4, exact
    const int h = lane >> 4;
    const int j = lane * 4;
    const float ad = a_dst[d * HEADS + h];
    const int beg = row_ptr[d], end = row_ptr[d + 1];
    float4 acc = {0.f, 0.f, 0.f, 0.f};
    float psum = 0.f;
    for (int base = beg; base < end; base += 64) {
        int cnt = end - base; if (cnt > 64) cnt = 64;
        int idx = base + lane;
        int myv = esrc[idx < end ? idx : end - 1];
        int i = 0;
        for (; i + 2 <= cnt; i += 2) {
            int s0 = __shfl(myv, i, 64);
            int s1 = __shfl(myv, i + 1, 64);
            float as0 = a_src[s0 * HEADS + h];
            float as1 = a_src[s1 * HEADS + h];
            uint2 g0 = *(const uint2*)(hh + (size_t)s0 * HC + j);
            uint2 g1 = *(const uint2*)(hh + (size_t)s1 * HC + j);
            float e0 = as0 + ad; e0 = e0 > 0.f ? e0 : NEG_SLOPE * e0;
            float e1 = as1 + ad; e1 = e1 > 0.f ? e1 : NEG_SLOPE * e1;
            float p0 = __expf(e0), p1 = __expf(e1);
            psum += p0 + p1;
            acc.x += p0 * __uint_as_float(g0.x << 16) + p1 * __uint_as_float(g1.x << 16);
            acc.y += p0 * __uint_as_float(g0.x & 0xffff0000u) + p1 * __uint_as_float(g1.x & 0xffff0000u);
            acc.z += p0 * __uint_as_float(g0.y << 16) + p1 * __uint_as_float(g1.y << 16);
            acc.w += p0 * __uint_as_float(g0.y & 0xffff0000u) + p1 * __uint_as_float(g1.y & 0xffff0000u);
        }
        if (i < cnt) {
            int s0 = __shfl(myv, i, 64);
            float as0 = a_src[s0 * HEADS + h];
            uint2 g0 = *(const uint2*)(hh + (size_t)s0 * HC + j);
            float e0 = as0 + ad; e0 = e0 > 0.f ? e0 : NEG_SLOPE * e0;
            float p0 = __expf(e0);
            psum += p0;
            acc.x += p0 * __uint_as_float(g0.x << 16);
            acc.y += p0 * __uint_as_float(g0.x & 0xffff0000u);
            acc.z += p0 * __uint_as_float(g0.y << 16);
            acc.w += p0 * __uint_as_float(g0.y & 0xffff0000u);
        }
    }
    const float inv = 1.f / (psum + 1e-16f);
    const float4 bb = *(const float4*)(bias + j);
    float4 v;
    v.x = acc.x * inv + bb.x; v.y = acc.y * inv + bb.y;
    v.z = acc.z * inv + bb.z; v.w = acc.w * inv + bb.w;
    v.x = v.x > 0.f ? v.x : (__expf(v.x) - 1.f);
    v.y = v.y > 0.f ? v.y : (__expf(v.y) - 1.f);
    v.z = v.z > 0.f ? v.z : (__expf(v.z) - 1.f);
    v.w = v.w > 0.f ? v.w : (__expf(v.w) - 1.f);
    uint2 pk;
    pk.x = pack_bf2(v.x, v.y);
    pk.y = pack_bf2(v.z, v.w);
    *(uint2*)(out + (size_t)d * HC + j) = pk;
}

// ======= MFMA out-proj + fused LayerNorm: out[M,128] = A[M,256] @ B -> LN =======
__global__ __launch_bounds__(256) void k_gemm_out(
        const unsigned short* __restrict__ A, const unsigned short* __restrict__ Bp,
        const float* __restrict__ b, const float* __restrict__ gamma,
        const float* __restrict__ beta, float* __restrict__ out) {
    const int lane = threadIdx.x & 63;
    const int quad = lane >> 5, c = lane & 31;
    const int m0 = blockIdx.x * 128 + (threadIdx.x >> 6) * 32;
    f32x16 acc[4];
#pragma unroll
    for (int nt = 0; nt < 4; ++nt)
#pragma unroll
        for (int i = 0; i < 16; ++i) acc[nt][i] = 0.f;
    int mrow = m0 + c; if (mrow >= N_NODES) mrow = N_NODES - 1;
    const size_t abase = (size_t)mrow * HC + quad * 8;
    for (int k0 = 0; k0 < HC; k0 += 16) {
        bf16x8 af = *(const bf16x8*)(A + abase + k0);
        const unsigned short* bk = Bp + ((size_t)(k0 >> 3) + quad) * (OUT_DIM * 8);
#pragma unroll
        for (int nt = 0; nt < 4; ++nt) {
            bf16x8 bf = *(const bf16x8*)(bk + (nt * 32 + c) * 8);
            acc[nt] = __builtin_amdgcn_mfma_f32_32x32x16_bf16(af, bf, acc[nt], 0, 0, 0);
        }
    }
    float bb[4], gg[4], be[4];
#pragma unroll
    for (int nt = 0; nt < 4; ++nt) {
        int col = nt * 32 + c;
        bb[nt] = b[col]; gg[nt] = gamma[col]; be[nt] = beta[col];
    }
#pragma unroll
    for (int reg = 0; reg < 16; ++reg) {
        int row = (reg & 3) + 8 * (reg >> 2) + 4 * quad;
        int m = m0 + row;
        float v[4];
        float s = 0.f, s2 = 0.f;
#pragma unroll
        for (int nt = 0; nt < 4; ++nt) {
            v[nt] = acc[nt][reg] + bb[nt];
            s += v[nt]; s2 += v[nt] * v[nt];
        }
#pragma unroll
        for (int mk = 1; mk < 32; mk <<= 1) {
            s += __shfl_xor(s, mk, 64);
            s2 += __shfl_xor(s2, mk, 64);
        }
        float mu = s * (1.f / OUT_DIM);
        float var = s2 * (1.f / OUT_DIM) - mu * mu;
        float inv = rsqrtf(var + LN_EPS);
        if (m < N_NODES) {
            size_t base = (size_t)m * OUT_DIM + c;
#pragma unroll
            for (int nt = 0; nt < 4; ++nt)
                out[base + nt * 32] = (v[nt] - mu) * inv * gg[nt] + be[nt];
        }
    }
}

extern "C" void kernel_launch(void* const* d_in, const int* in_sizes, int n_in,
                              void* d_out, int out_size, void* d_ws, size_t ws_size,
                              hipStream_t stream) {
    const float* x        = (const float*)d_in[0];
    const int*   ei       = (const int*)  d_in[1];
    const float* W_in     = (const float*)d_in[2];
    const float* b_in     = (const float*)d_in[3];
    const float* lin0_w   = (const float*)d_in[4];
    const float* att0_src = (const float*)d_in[5];
    const float* att0_dst = (const float*)d_in[6];
    const float* bias0    = (const float*)d_in[7];
    const float* lin1_w   = (const float*)d_in[8];
    const float* att1_src = (const float*)d_in[9];
    const float* att1_dst = (const float*)d_in[10];
    const float* bias1    = (const float*)d_in[11];
    const float* W_out    = (const float*)d_in[12];
    const float* b_out    = (const float*)d_in[13];
    const float* ln_gamma = (const float*)d_in[14];
    const float* ln_beta  = (const float*)d_in[15];
    float* out = (float*)d_out;

    unsigned short* us = (unsigned short*)d_ws;
    unsigned short* h_in_bf = us;                                  // N*HID
    unsigned short* hh_bf   = h_in_bf + (size_t)N_NODES * HID;     // N*HC
    unsigned short* feat_bf = hh_bf + (size_t)N_NODES * HC;        // N*HC
    unsigned short* p0      = feat_bf + (size_t)N_NODES * HC;      // 64*256
    unsigned short* p1      = p0 + HID * HC;                       // 256*256
    unsigned short* p2      = p1 + HC * HC;                        // 256*128
    float* a_src = (float*)(p2 + HC * OUT_DIM);
    float* a_dst = a_src + (size_t)N_NODES * HEADS;
    int* counts     = (int*)(a_dst + (size_t)N_NODES * HEADS);
    int* chunk_excl = counts + N_NODES;
    int* bsum       = chunk_excl + N_NODES;
    int* row_ptr    = bsum + NB;
    int* cursor     = row_ptr + N_NODES + 1;
    int* esrc       = cursor + N_NODES;

    // 1. input projection (bf16 out) + weight packing
    k_in_proj<<<(N_NODES * HID) / 256, 256, 0, stream>>>(x, W_in, b_in, h_in_bf);
    k_wpack<<<(HID * HC + HC * HC + HC * OUT_DIM + 255) / 256, 256, 0, stream>>>(
        lin0_w, lin1_w, W_out, p0, p1, p2);

    // 2. CSR build (once; shared by both GAT layers)
    hipMemsetAsync(counts, 0, N_NODES * sizeof(int), stream);
    k_hist<<<(EP + 255) / 256, 256, 0, stream>>>(ei, counts);
    k_scan1<<<NB, SCAN_B, 0, stream>>>(counts, chunk_excl, bsum);
    k_scan2<<<1, 1, 0, stream>>>(bsum);
    k_scan3<<<NB, SCAN_B, 0, stream>>>(chunk_excl, bsum, row_ptr, cursor);
    k_scatter<<<(EP + 255) / 256, 256, 0, stream>>>(ei, cursor, esrc);

    const int gemm_grid = (N_NODES + 127) / 128;   // 391
    const int dots_grid = N_NODES / 2 / 4;         // 6250 (wave=2 nodes, 4 waves/blk)

    // ---- GAT layer 0 ----
    k_gemm_lin<HID><<<gemm_grid, 256, 0, stream>>>(h_in_bf, p0, hh_bf);
    k_att_dots<<<dots_grid, 256, 0, stream>>>(hh_bf, att0_src, att0_dst, a_src, a_dst);
    k_gat_agg<<<N_NODES / 4, 256, 0, stream>>>(row_ptr, esrc, hh_bf, a_src, a_dst,
                                               bias0, feat_bf);

    // ---- GAT layer 1 ----
    k_gemm_lin<HC><<<gemm_grid, 256, 0, stream>>>(feat_bf, p1, hh_bf);
    k_att_dots<<<dots_grid, 256, 0, stream>>>(hh_bf, att1_src, att1_dst, a_src, a_dst);
    k_gat_agg<<<N_NODES / 4, 256, 0, stream>>>(row_ptr, esrc, hh_bf, a_src, a_dst,
                                               bias1, feat_bf);

    // ---- output projection + LayerNorm ----
    k_gemm_out<<<gemm_grid, 256, 0, stream>>>(feat_bf, p2, b_out, ln_gamma, ln_beta, out);
}